// Round 1
// baseline (176.772 us; speedup 1.0000x reference)
//
#include <hip/hip_runtime.h>

#define CH    128
#define HH    56
#define WW    56
#define BB    32
#define NPIX  (BB * HH * WW)   // 100352
#define P2    64               // pixels per block, stats pass
#define P3    32               // pixels per block, output pass
#define NSLOT 32               // atomic spreading slots

struct alignas(16) U2 { unsigned long long x, y; };

// ---------------- zero accumulators (32 slots x 256 u64) ----------------
__global__ __launch_bounds__(256) void zero_k(unsigned long long* __restrict__ a) {
    a[(size_t)blockIdx.x * 256 + threadIdx.x] = 0ull;
}

// ---------------- pack x signs: one wave per pixel ----------------
__global__ __launch_bounds__(256) void pack_x_k(const float* __restrict__ x, U2* __restrict__ xb) {
    int wave = threadIdx.x >> 6;
    int lane = threadIdx.x & 63;
    int p = blockIdx.x * 4 + wave;           // grid = NPIX/4 exactly
    const float* px = x + (size_t)p * CH;
    unsigned long long b0 = __ballot(px[lane] >= 0.0f);
    unsigned long long b1 = __ballot(px[lane + 64] >= 0.0f);
    if (lane == 0) { xb[p].x = b0; xb[p].y = b1; }
}

// ---------------- pack W signs: block per tap, thread per co ----------------
// W is HWIO: W[kh][kw][ci][co]; bit ci of word0/word1 matches pack_x mapping.
__global__ __launch_bounds__(128) void pack_w_k(const float* __restrict__ Wt, U2* __restrict__ wb) {
    int tap = blockIdx.x;     // 0..8
    int co  = threadIdx.x;    // 0..127
    const float* base = Wt + (size_t)tap * CH * CH + co;
    unsigned long long b0 = 0, b1 = 0;
    #pragma unroll 4
    for (int ci = 0; ci < 64; ++ci) {
        if (base[(size_t)ci * CH]        >= 0.0f) b0 |= 1ull << ci;
        if (base[(size_t)(ci + 64) * CH] >= 0.0f) b1 |= 1ull << ci;
    }
    wb[tap * CH + co].x = b0;
    wb[tap * CH + co].y = b1;
}

// ---------------- binarized conv for one (pixel, co) ----------------
__device__ __forceinline__ int conv_pc(const U2* __restrict__ xb, const U2 wb[9],
                                       int b, int h, int w) {
    const U2* rowbase = xb + (size_t)b * (HH * WW);
    int mis = 0, valid = 0;
    #pragma unroll
    for (int kh = 0; kh < 3; ++kh) {
        int ih = h + kh - 1;
        if ((unsigned)ih >= (unsigned)HH) continue;
        #pragma unroll
        for (int kw = 0; kw < 3; ++kw) {
            int iw = w + kw - 1;
            if ((unsigned)iw >= (unsigned)WW) continue;
            U2 xv = rowbase[ih * WW + iw];
            mis += __popcll(xv.x ^ wb[kh * 3 + kw].x);
            mis += __popcll(xv.y ^ wb[kh * 3 + kw].y);
            valid += CH;
        }
    }
    return valid - 2 * mis;
}

// ---------------- stats pass: per-channel sum(r), sum(r^2) ----------------
__global__ __launch_bounds__(128) void stats_k(const U2* __restrict__ xb, const U2* __restrict__ wbg,
                                               unsigned long long* __restrict__ accum) {
    int c = threadIdx.x;
    U2 wb[9];
    #pragma unroll
    for (int t = 0; t < 9; ++t) wb[t] = wbg[t * CH + c];
    int p0 = blockIdx.x * P2;
    unsigned int s1 = 0, s2 = 0;   // max: 64*1152 and 64*1152^2 < 2^31
    for (int i = 0; i < P2; ++i) {
        int p  = p0 + i;           // uniform across block
        int w  = p % WW;
        int hb = p / WW;
        int h  = hb % HH;
        int b  = hb / HH;
        int y = conv_pc(xb, wb, b, h, w);
        unsigned int r = (y > 0) ? (unsigned int)y : 0u;
        s1 += r;
        s2 += r * r;
    }
    int slot = blockIdx.x & (NSLOT - 1);
    atomicAdd(&accum[slot * 256 + c],       (unsigned long long)s1);
    atomicAdd(&accum[slot * 256 + 128 + c], (unsigned long long)s2);
}

// ---------------- finalize BN: scale/shift per channel ----------------
__global__ __launch_bounds__(128) void finalize_k(const unsigned long long* __restrict__ accum,
                                                  const float* __restrict__ gamma,
                                                  const float* __restrict__ beta,
                                                  float2* __restrict__ ss) {
    int c = threadIdx.x;
    unsigned long long s1 = 0, s2 = 0;
    #pragma unroll
    for (int s = 0; s < NSLOT; ++s) {
        s1 += accum[s * 256 + c];
        s2 += accum[s * 256 + 128 + c];
    }
    double N    = (double)NPIX;
    double mean = (double)s1 / N;
    double var  = (double)s2 / N - mean * mean;
    double rstd = 1.0 / sqrt(var + 1e-3);
    double sc   = (double)gamma[c] * rstd;
    float2 v;
    v.x = (float)sc;
    v.y = (float)((double)beta[c] - mean * sc);
    ss[c] = v;
}

// ---------------- output pass: out = relu(conv)*scale + shift + x ----------------
__global__ __launch_bounds__(128) void out_k(const U2* __restrict__ xb, const U2* __restrict__ wbg,
                                             const float2* __restrict__ ss,
                                             const float* __restrict__ x,
                                             float* __restrict__ out) {
    int c = threadIdx.x;
    U2 wb[9];
    #pragma unroll
    for (int t = 0; t < 9; ++t) wb[t] = wbg[t * CH + c];
    float2 s = ss[c];
    int p0 = blockIdx.x * P3;
    for (int i = 0; i < P3; ++i) {
        int p  = p0 + i;
        int w  = p % WW;
        int hb = p / WW;
        int h  = hb % HH;
        int b  = hb / HH;
        int y = conv_pc(xb, wb, b, h, w);
        float r = (float)(y > 0 ? y : 0);
        size_t idx = (size_t)p * CH + c;
        out[idx] = fmaf(r, s.x, s.y + x[idx]);
    }
}

extern "C" void kernel_launch(void* const* d_in, const int* in_sizes, int n_in,
                              void* d_out, int out_size, void* d_ws, size_t ws_size,
                              hipStream_t stream) {
    const float* x     = (const float*)d_in[0];
    const float* Wt    = (const float*)d_in[1];
    const float* gamma = (const float*)d_in[2];
    const float* beta  = (const float*)d_in[3];
    float* out = (float*)d_out;

    char* ws = (char*)d_ws;
    // layout (16B aligned offsets)
    U2* xb = (U2*)ws;                                  // NPIX*16 = 1,605,632 B
    U2* wb = (U2*)(ws + 1605632);                      // 9*128*16 = 18,432 B
    unsigned long long* accum = (unsigned long long*)(ws + 1624064); // 32*256*8 = 65,536 B
    float2* ss = (float2*)(ws + 1689600);              // 128*8 = 1,024 B

    hipLaunchKernelGGL(zero_k,    dim3(NSLOT),     dim3(256), 0, stream, accum);
    hipLaunchKernelGGL(pack_x_k,  dim3(NPIX / 4),  dim3(256), 0, stream, x, xb);
    hipLaunchKernelGGL(pack_w_k,  dim3(9),         dim3(128), 0, stream, Wt, wb);
    hipLaunchKernelGGL(stats_k,   dim3(NPIX / P2), dim3(128), 0, stream, xb, wb, accum);
    hipLaunchKernelGGL(finalize_k,dim3(1),         dim3(128), 0, stream, accum, gamma, beta, ss);
    hipLaunchKernelGGL(out_k,     dim3(NPIX / P3), dim3(128), 0, stream, xb, wb, ss, x, out);
}

// Round 2
// 105.685 us; speedup vs baseline: 1.6726x; 1.6726x over previous
//
#include <hip/hip_runtime.h>

#define CH    128
#define HH    56
#define WW    56
#define BB    32
#define NPIX  (BB * HH * WW)   // 100352
#define NSLOT 32               // atomic spreading slots

struct alignas(16) U2 { unsigned long long x, y; };

// ---------------- pack x signs: one wave per pixel ----------------
__global__ __launch_bounds__(256) void pack_x_k(const float* __restrict__ x, U2* __restrict__ xb) {
    int wave = threadIdx.x >> 6;
    int lane = threadIdx.x & 63;
    int p = blockIdx.x * 4 + wave;           // grid = NPIX/4 exactly
    const float* px = x + (size_t)p * CH;
    unsigned long long b0 = __ballot(px[lane] >= 0.0f);
    unsigned long long b1 = __ballot(px[lane + 64] >= 0.0f);
    if (lane == 0) { xb[p].x = b0; xb[p].y = b1; }
}

// ---------------- pack W signs: block per tap, thread per co ----------------
// W is HWIO: W[kh][kw][ci][co]; bit ci of word0/word1 matches pack_x mapping.
__global__ __launch_bounds__(128) void pack_w_k(const float* __restrict__ Wt, U2* __restrict__ wb) {
    int tap = blockIdx.x;     // 0..8
    int co  = threadIdx.x;    // 0..127
    const float* base = Wt + (size_t)tap * CH * CH + co;
    unsigned long long b0 = 0, b1 = 0;
    #pragma unroll 4
    for (int ci = 0; ci < 64; ++ci) {
        if (base[(size_t)ci * CH]        >= 0.0f) b0 |= 1ull << ci;
        if (base[(size_t)(ci + 64) * CH] >= 0.0f) b1 |= 1ull << ci;
    }
    wb[tap * CH + co].x = b0;
    wb[tap * CH + co].y = b1;
}

// ---------------- fused conv pass (stats or output) ----------------
// Block = (h, b): rows h-1..h+1 staged in LDS (zero-padded halo).
// 256 threads: c = tid&127 (output channel), g = tid>>7 (column half: 28 cols).
// Sliding window: 3 new LDS reads per pixel; SAME padding via corr subtraction.
template<bool STATS>
__global__ __launch_bounds__(256) void conv_k(const U2* __restrict__ xb,
                                              const U2* __restrict__ wbg,
                                              unsigned long long* __restrict__ accum,
                                              const float2* __restrict__ ss,
                                              const float* __restrict__ x,
                                              float* __restrict__ out) {
    __shared__ U2 lx[3][64];
    int h = blockIdx.x;       // 0..55
    int b = blockIdx.y;       // 0..31
    int tid = threadIdx.x;
    int c = tid & (CH - 1);
    int g = tid >> 7;

    // stage rows h-1..h+1; LDS col j holds image col j-1; cols 0 and 57..63 zero
    if (tid < 192) {
        int r = tid >> 6, j = tid & 63;
        int ih = h - 1 + r;
        U2 v; v.x = 0ull; v.y = 0ull;
        if (j >= 1 && j <= 56 && (unsigned)ih < (unsigned)HH)
            v = xb[((size_t)b * HH + ih) * WW + (j - 1)];
        lx[r][j] = v;
    }

    // per-thread weights + padding corrections (corr[t] = 128 - 2*popc(wb[t]))
    U2 wb[3][3];
    int corr[3][3];
    #pragma unroll
    for (int r = 0; r < 3; ++r)
        #pragma unroll
        for (int k = 0; k < 3; ++k) {
            U2 wv = wbg[(r * 3 + k) * CH + c];
            wb[r][k] = wv;
            corr[r][k] = CH - 2 * (__popcll(wv.x) + __popcll(wv.y));
        }
    bool v0 = (h > 0), v2 = (h < HH - 1);
    int corrR = 0, ccol0 = corr[1][0], ccol2 = corr[1][2];
    if (!v0) corrR += corr[0][0] + corr[0][1] + corr[0][2];
    else     { ccol0 += corr[0][0]; ccol2 += corr[0][2]; }
    if (!v2) corrR += corr[2][0] + corr[2][1] + corr[2][2];
    else     { ccol0 += corr[2][0]; ccol2 += corr[2][2]; }

    __syncthreads();

    int w0 = g * 28;
    U2 A[3], Bc[3], Cc[3];
    #pragma unroll
    for (int r = 0; r < 3; ++r) { A[r] = lx[r][w0]; Bc[r] = lx[r][w0 + 1]; }

    unsigned int s1 = 0, s2 = 0;
    float2 s;
    if (!STATS) s = ss[c];
    size_t pbase = ((size_t)b * HH + h) * WW;

    #pragma unroll 4
    for (int i = 0; i < 28; ++i) {
        int w = w0 + i;
        #pragma unroll
        for (int r = 0; r < 3; ++r) Cc[r] = lx[r][w + 2];
        int mis = 0;
        #pragma unroll
        for (int r = 0; r < 3; ++r) {
            mis += __popcll(A[r].x  ^ wb[r][0].x) + __popcll(A[r].y  ^ wb[r][0].y);
            mis += __popcll(Bc[r].x ^ wb[r][1].x) + __popcll(Bc[r].y ^ wb[r][1].y);
            mis += __popcll(Cc[r].x ^ wb[r][2].x) + __popcll(Cc[r].y ^ wb[r][2].y);
        }
        int y = 9 * CH - 2 * mis - corrR;
        if (w == 0)      y -= ccol0;
        if (w == WW - 1) y -= ccol2;
        int rr = y > 0 ? y : 0;
        if (STATS) {
            s1 += (unsigned)rr;
            s2 += (unsigned)(rr * rr);   // <= 28*1152^2 < 2^31
        } else {
            size_t idx = (pbase + w) * CH + c;
            out[idx] = fmaf((float)rr, s.x, s.y + x[idx]);
        }
        #pragma unroll
        for (int r = 0; r < 3; ++r) { A[r] = Bc[r]; Bc[r] = Cc[r]; }
    }
    if (STATS) {
        int slot = (blockIdx.x + blockIdx.y * HH) & (NSLOT - 1);
        atomicAdd(&accum[slot * 256 + c],       (unsigned long long)s1);
        atomicAdd(&accum[slot * 256 + 128 + c], (unsigned long long)s2);
    }
}

// ---------------- finalize BN: scale/shift per channel ----------------
__global__ __launch_bounds__(128) void finalize_k(const unsigned long long* __restrict__ accum,
                                                  const float* __restrict__ gamma,
                                                  const float* __restrict__ beta,
                                                  float2* __restrict__ ss) {
    int c = threadIdx.x;
    unsigned long long s1 = 0, s2 = 0;
    #pragma unroll
    for (int s = 0; s < NSLOT; ++s) {
        s1 += accum[s * 256 + c];
        s2 += accum[s * 256 + 128 + c];
    }
    double N    = (double)NPIX;
    double mean = (double)s1 / N;
    double var  = (double)s2 / N - mean * mean;
    double rstd = 1.0 / sqrt(var + 1e-3);
    double sc   = (double)gamma[c] * rstd;
    float2 v;
    v.x = (float)sc;
    v.y = (float)((double)beta[c] - mean * sc);
    ss[c] = v;
}

extern "C" void kernel_launch(void* const* d_in, const int* in_sizes, int n_in,
                              void* d_out, int out_size, void* d_ws, size_t ws_size,
                              hipStream_t stream) {
    const float* x     = (const float*)d_in[0];
    const float* Wt    = (const float*)d_in[1];
    const float* gamma = (const float*)d_in[2];
    const float* beta  = (const float*)d_in[3];
    float* out = (float*)d_out;

    char* ws = (char*)d_ws;
    U2* xb = (U2*)ws;                                               // 1,605,632 B
    U2* wb = (U2*)(ws + 1605632);                                   // 18,432 B
    unsigned long long* accum = (unsigned long long*)(ws + 1624064);// 65,536 B
    float2* ss = (float2*)(ws + 1689600);                           // 1,024 B

    hipMemsetAsync(accum, 0, NSLOT * 256 * sizeof(unsigned long long), stream);
    hipLaunchKernelGGL(pack_x_k,     dim3(NPIX / 4), dim3(256), 0, stream, x, xb);
    hipLaunchKernelGGL(pack_w_k,     dim3(9),        dim3(128), 0, stream, Wt, wb);
    hipLaunchKernelGGL(conv_k<true>, dim3(HH, BB),   dim3(256), 0, stream,
                       xb, wb, accum, (const float2*)ss, x, out);
    hipLaunchKernelGGL(finalize_k,   dim3(1),        dim3(128), 0, stream, accum, gamma, beta, ss);
    hipLaunchKernelGGL(conv_k<false>,dim3(HH, BB),   dim3(256), 0, stream,
                       xb, wb, accum, (const float2*)ss, x, out);
}

// Round 3
// 84.523 us; speedup vs baseline: 2.0914x; 1.2504x over previous
//
#include <hip/hip_runtime.h>

#define CH    128
#define HH    56
#define WW    56
#define BB    32
#define NPIX  (BB * HH * WW)   // 100352
#define NSLOT 32

struct alignas(16) U2 { unsigned long long x, y; };

// ---------------- pack x signs: one wave per pixel, float2/lane ----------------
// bit l of word0 = sign(x[ch 2l]); bit l of word1 = sign(x[ch 2l+1]).
// (Any fixed channel permutation works as long as pack_w matches.)
__global__ __launch_bounds__(256) void pack_x_k(const float* __restrict__ x, U2* __restrict__ xb) {
    int wave = threadIdx.x >> 6;
    int lane = threadIdx.x & 63;
    int p = blockIdx.x * 4 + wave;           // grid = NPIX/4 exactly
    const float2* px = (const float2*)(x + (size_t)p * CH);
    float2 v = px[lane];
    unsigned long long b0 = __ballot(v.x >= 0.0f);
    unsigned long long b1 = __ballot(v.y >= 0.0f);
    if (lane == 0) { xb[p].x = b0; xb[p].y = b1; }
}

// ---------------- pack W signs: block per tap, thread per co ----------------
// W is HWIO: W[kh][kw][ci][co]; matches pack_x permutation (even/odd split).
__global__ __launch_bounds__(128) void pack_w_k(const float* __restrict__ Wt, U2* __restrict__ wb) {
    int tap = blockIdx.x;     // 0..8
    int co  = threadIdx.x;    // 0..127
    const float* base = Wt + (size_t)tap * CH * CH + co;
    unsigned long long b0 = 0, b1 = 0;
    #pragma unroll 4
    for (int ci = 0; ci < 64; ++ci) {
        if (base[(size_t)(2 * ci)     * CH] >= 0.0f) b0 |= 1ull << ci;
        if (base[(size_t)(2 * ci + 1) * CH] >= 0.0f) b1 |= 1ull << ci;
    }
    wb[tap * CH + co].x = b0;
    wb[tap * CH + co].y = b1;
}

// ---------------- conv + stats pass (optionally storing r as u16) ----------------
// Block = (h, b): rows h-1..h+1 staged in LDS (zero-padded halo).
// 256 threads: c = tid&127 (output channel), g = tid>>7 (column half: 28 cols).
template<bool STORE_R>
__global__ __launch_bounds__(256) void conv_stats_k(const U2* __restrict__ xb,
                                                    const U2* __restrict__ wbg,
                                                    unsigned long long* __restrict__ accum,
                                                    unsigned short* __restrict__ rb) {
    __shared__ U2 lx[3][64];
    int h = blockIdx.x;       // 0..55
    int b = blockIdx.y;       // 0..31
    int tid = threadIdx.x;
    int c = tid & (CH - 1);
    int g = tid >> 7;

    if (tid < 192) {
        int r = tid >> 6, j = tid & 63;
        int ih = h - 1 + r;
        U2 v; v.x = 0ull; v.y = 0ull;
        if (j >= 1 && j <= 56 && (unsigned)ih < (unsigned)HH)
            v = xb[((size_t)b * HH + ih) * WW + (j - 1)];
        lx[r][j] = v;
    }

    U2 wb[3][3];
    int corr[3][3];
    #pragma unroll
    for (int r = 0; r < 3; ++r)
        #pragma unroll
        for (int k = 0; k < 3; ++k) {
            U2 wv = wbg[(r * 3 + k) * CH + c];
            wb[r][k] = wv;
            corr[r][k] = CH - 2 * (__popcll(wv.x) + __popcll(wv.y));
        }
    bool v0 = (h > 0), v2 = (h < HH - 1);
    int corrR = 0, ccol0 = corr[1][0], ccol2 = corr[1][2];
    if (!v0) corrR += corr[0][0] + corr[0][1] + corr[0][2];
    else     { ccol0 += corr[0][0]; ccol2 += corr[0][2]; }
    if (!v2) corrR += corr[2][0] + corr[2][1] + corr[2][2];
    else     { ccol0 += corr[2][0]; ccol2 += corr[2][2]; }

    __syncthreads();

    int w0 = g * 28;
    U2 A[3], Bc[3], Cc[3];
    #pragma unroll
    for (int r = 0; r < 3; ++r) { A[r] = lx[r][w0]; Bc[r] = lx[r][w0 + 1]; }

    unsigned int s1 = 0, s2 = 0;
    size_t pbase = ((size_t)b * HH + h) * WW;
    unsigned short* rout = rb + (pbase + w0) * CH + c;

    #pragma unroll
    for (int i = 0; i < 28; ++i) {
        #pragma unroll
        for (int r = 0; r < 3; ++r) Cc[r] = lx[r][w0 + i + 2];
        int mis = 0;
        #pragma unroll
        for (int r = 0; r < 3; ++r) {
            mis += __popcll(A[r].x  ^ wb[r][0].x) + __popcll(A[r].y  ^ wb[r][0].y);
            mis += __popcll(Bc[r].x ^ wb[r][1].x) + __popcll(Bc[r].y ^ wb[r][1].y);
            mis += __popcll(Cc[r].x ^ wb[r][2].x) + __popcll(Cc[r].y ^ wb[r][2].y);
        }
        int y = 9 * CH - 2 * mis - corrR;
        if (i == 0)  y -= (g == 0) ? ccol0 : 0;   // w == 0
        if (i == 27) y -= (g == 1) ? ccol2 : 0;   // w == 55
        int rr = y > 0 ? y : 0;
        s1 += (unsigned)rr;
        s2 += (unsigned)(rr * rr);   // <= 28*1152^2 < 2^31
        if (STORE_R) rout[(size_t)i * CH] = (unsigned short)rr;
        #pragma unroll
        for (int r = 0; r < 3; ++r) { A[r] = Bc[r]; Bc[r] = Cc[r]; }
    }
    int slot = (blockIdx.x + blockIdx.y * HH) & (NSLOT - 1);
    atomicAdd(&accum[slot * 256 + c],       (unsigned long long)s1);
    atomicAdd(&accum[slot * 256 + 128 + c], (unsigned long long)s2);
}

// ---------------- finalize BN: scale/shift per channel ----------------
__global__ __launch_bounds__(128) void finalize_k(const unsigned long long* __restrict__ accum,
                                                  const float* __restrict__ gamma,
                                                  const float* __restrict__ beta,
                                                  float2* __restrict__ ss) {
    int c = threadIdx.x;
    unsigned long long s1 = 0, s2 = 0;
    #pragma unroll
    for (int s = 0; s < NSLOT; ++s) {
        s1 += accum[s * 256 + c];
        s2 += accum[s * 256 + 128 + c];
    }
    double N    = (double)NPIX;
    double mean = (double)s1 / N;
    double var  = (double)s2 / N - mean * mean;
    double rstd = 1.0 / sqrt(var + 1e-3);
    double sc   = (double)gamma[c] * rstd;
    float2 v;
    v.x = (float)sc;
    v.y = (float)((double)beta[c] - mean * sc);
    ss[c] = v;
}

// ---------------- streaming output: out = r*scale + shift + x ----------------
__global__ __launch_bounds__(256) void out_stream_k(const unsigned short* __restrict__ rb,
                                                    const float2* __restrict__ ss,
                                                    const float* __restrict__ x,
                                                    float* __restrict__ out) {
    int idx4 = blockIdx.x * 256 + threadIdx.x;     // grid covers NPIX*CH/4 exactly
    int c4 = idx4 & (CH / 4 - 1);
    ushort4 r = ((const ushort4*)rb)[idx4];
    float4 xv = ((const float4*)x)[idx4];
    float2 s0 = ss[c4 * 4 + 0], s1 = ss[c4 * 4 + 1];
    float2 s2 = ss[c4 * 4 + 2], s3 = ss[c4 * 4 + 3];
    float4 o;
    o.x = fmaf((float)r.x, s0.x, s0.y + xv.x);
    o.y = fmaf((float)r.y, s1.x, s1.y + xv.y);
    o.z = fmaf((float)r.z, s2.x, s2.y + xv.z);
    o.w = fmaf((float)r.w, s3.x, s3.y + xv.w);
    ((float4*)out)[idx4] = o;
}

// ---------------- fallback output pass (recompute conv) for small ws ----------------
__global__ __launch_bounds__(256) void conv_out_k(const U2* __restrict__ xb,
                                                  const U2* __restrict__ wbg,
                                                  const float2* __restrict__ ss,
                                                  const float* __restrict__ x,
                                                  float* __restrict__ out) {
    __shared__ U2 lx[3][64];
    int h = blockIdx.x, b = blockIdx.y;
    int tid = threadIdx.x;
    int c = tid & (CH - 1);
    int g = tid >> 7;
    if (tid < 192) {
        int r = tid >> 6, j = tid & 63;
        int ih = h - 1 + r;
        U2 v; v.x = 0ull; v.y = 0ull;
        if (j >= 1 && j <= 56 && (unsigned)ih < (unsigned)HH)
            v = xb[((size_t)b * HH + ih) * WW + (j - 1)];
        lx[r][j] = v;
    }
    U2 wb[3][3];
    int corr[3][3];
    #pragma unroll
    for (int r = 0; r < 3; ++r)
        #pragma unroll
        for (int k = 0; k < 3; ++k) {
            U2 wv = wbg[(r * 3 + k) * CH + c];
            wb[r][k] = wv;
            corr[r][k] = CH - 2 * (__popcll(wv.x) + __popcll(wv.y));
        }
    bool v0 = (h > 0), v2 = (h < HH - 1);
    int corrR = 0, ccol0 = corr[1][0], ccol2 = corr[1][2];
    if (!v0) corrR += corr[0][0] + corr[0][1] + corr[0][2];
    else     { ccol0 += corr[0][0]; ccol2 += corr[0][2]; }
    if (!v2) corrR += corr[2][0] + corr[2][1] + corr[2][2];
    else     { ccol0 += corr[2][0]; ccol2 += corr[2][2]; }
    __syncthreads();
    int w0 = g * 28;
    U2 A[3], Bc[3], Cc[3];
    #pragma unroll
    for (int r = 0; r < 3; ++r) { A[r] = lx[r][w0]; Bc[r] = lx[r][w0 + 1]; }
    float2 s = ss[c];
    size_t pbase = ((size_t)b * HH + h) * WW;
    #pragma unroll
    for (int i = 0; i < 28; ++i) {
        int w = w0 + i;
        #pragma unroll
        for (int r = 0; r < 3; ++r) Cc[r] = lx[r][w + 2];
        int mis = 0;
        #pragma unroll
        for (int r = 0; r < 3; ++r) {
            mis += __popcll(A[r].x  ^ wb[r][0].x) + __popcll(A[r].y  ^ wb[r][0].y);
            mis += __popcll(Bc[r].x ^ wb[r][1].x) + __popcll(Bc[r].y ^ wb[r][1].y);
            mis += __popcll(Cc[r].x ^ wb[r][2].x) + __popcll(Cc[r].y ^ wb[r][2].y);
        }
        int y = 9 * CH - 2 * mis - corrR;
        if (i == 0)  y -= (g == 0) ? ccol0 : 0;
        if (i == 27) y -= (g == 1) ? ccol2 : 0;
        int rr = y > 0 ? y : 0;
        size_t idx = (pbase + w) * CH + c;
        out[idx] = fmaf((float)rr, s.x, s.y + x[idx]);
        #pragma unroll
        for (int r = 0; r < 3; ++r) { A[r] = Bc[r]; Bc[r] = Cc[r]; }
    }
}

extern "C" void kernel_launch(void* const* d_in, const int* in_sizes, int n_in,
                              void* d_out, int out_size, void* d_ws, size_t ws_size,
                              hipStream_t stream) {
    const float* x     = (const float*)d_in[0];
    const float* Wt    = (const float*)d_in[1];
    const float* gamma = (const float*)d_in[2];
    const float* beta  = (const float*)d_in[3];
    float* out = (float*)d_out;

    char* ws = (char*)d_ws;
    U2* xb = (U2*)ws;                                               // 1,605,632 B
    U2* wb = (U2*)(ws + 1605632);                                   // 18,432 B
    unsigned long long* accum = (unsigned long long*)(ws + 1624064);// 65,536 B
    float2* ss = (float2*)(ws + 1689600);                           // 1,024 B
    unsigned short* rb = (unsigned short*)(ws + 1690624);           // 25,690,112 B
    const size_t WS_NEEDED = 1690624ull + (size_t)NPIX * CH * 2;

    hipMemsetAsync(accum, 0, NSLOT * 256 * sizeof(unsigned long long), stream);
    hipLaunchKernelGGL(pack_x_k, dim3(NPIX / 4), dim3(256), 0, stream, x, xb);
    hipLaunchKernelGGL(pack_w_k, dim3(9),        dim3(128), 0, stream, Wt, wb);

    if (ws_size >= WS_NEEDED) {
        hipLaunchKernelGGL(conv_stats_k<true>, dim3(HH, BB), dim3(256), 0, stream,
                           xb, wb, accum, rb);
        hipLaunchKernelGGL(finalize_k, dim3(1), dim3(128), 0, stream, accum, gamma, beta, ss);
        hipLaunchKernelGGL(out_stream_k, dim3(NPIX * CH / 4 / 256), dim3(256), 0, stream,
                           rb, (const float2*)ss, x, out);
    } else {
        hipLaunchKernelGGL(conv_stats_k<false>, dim3(HH, BB), dim3(256), 0, stream,
                           xb, wb, accum, rb);
        hipLaunchKernelGGL(finalize_k, dim3(1), dim3(128), 0, stream, accum, gamma, beta, ss);
        hipLaunchKernelGGL(conv_out_k, dim3(HH, BB), dim3(256), 0, stream,
                           xb, wb, (const float2*)ss, x, out);
    }
}